// Round 3
// baseline (78865.930 us; speedup 1.0000x reference)
//
#include <hip/hip_runtime.h>

#define TT 512

typedef _Float16 f16;
typedef _Float16 half8 __attribute__((ext_vector_type(8)));
typedef float f32x4 __attribute__((ext_vector_type(4)));

#define MFMA(a,b,c) __builtin_amdgcn_mfma_f32_16x16x32_f16((a),(b),(c),0,0,0)
#define LOSC  2048.0f
#define RLOSC 0.00048828125f   // 1/2048

// LDS partial layout: per-wave region of 16 rows, row stride 18 floats.
#define RS  18
#define WSZ (16*RS)      // 288 floats per wave region
#define LSZ (16*WSZ)     // 4608 floats per buffer (18.4 KB)

__device__ __forceinline__ half8 ldh8(const f16* p){ return *(const half8*)p; }
__device__ __forceinline__ float sgm(float x){ return 1.f/(1.f+__expf(-x)); }
// act kinds: 0 tanh, 1 sigmoid, 2 relu, 3 identity
__device__ __forceinline__ float applyact(int k, float x){
  if (k==0) return tanhf(x);
  if (k==1) return sgm(x);
  if (k==2) return fmaxf(x,0.f);
  return x;
}

// ---- grid barrier v2: per-block monotonic slot store + all-scan ---------------
__device__ __forceinline__ void gbar(unsigned* bar, unsigned ph, int b, int wid, int lane){
  __syncthreads();
  const unsigned tgt = ph + 1u;
  if (wid == 0){
    if (lane == 0){
      __builtin_amdgcn_fence(__ATOMIC_RELEASE, "agent");
      __hip_atomic_store(&bar[b*4], tgt, __ATOMIC_RELEASE, __HIP_MEMORY_SCOPE_AGENT);
    }
    for (;;){
      int ok = 1;
      #pragma unroll
      for (int j=0;j<4;j++){
        unsigned v = __hip_atomic_load(&bar[(lane + 64*j)*4], __ATOMIC_RELAXED, __HIP_MEMORY_SCOPE_AGENT);
        ok &= (v >= tgt);
      }
      if (__all(ok)) break;
      __builtin_amdgcn_s_sleep(1);
    }
    if (lane == 0) __builtin_amdgcn_fence(__ATOMIC_ACQUIRE, "agent");
  }
  __syncthreads();
}

// ---- line-touch prefetch: each lane dword-loads a distinct 64B chunk ----------
// Tile enumerated as id = c*96 + a*48 + r  (c: K-chunk of 32 halfs; a: hi/lo;
// r<16: W g-row c0+r; r<32: W a-row 1024+c0+(r-16); r>=32: A row m0+(r-32)).
// One 64-lane load = 64 line fills in flight -> kills the latency serialization
// caused by the gbar acquire's L2 invalidate.
__device__ __forceinline__ void touch_tiles(
  const f16* __restrict__ Wh, const f16* __restrict__ Wl, int Kst, int c0, int kk,
  const f16* __restrict__ Ah, const f16* __restrict__ Al, int m0, int ak,
  int nch, int wlo, int lane)
{
  unsigned acc = 0;
  const int tot = (wlo ? 96 : 48) * nch;
  for (int base = 0; base < tot; base += 64){
    int id = base + lane;
    if (id >= tot) id -= tot;
    int c, a, r;
    if (wlo){ c = id/96; int ra = id - c*96; a = ra/48; r = ra - a*48; }
    else    { c = id/48; r = id - c*48; a = 0; }
    const unsigned* p;
    if (r < 32){
      const f16* wb = a ? Wl : Wh;
      int row = (r<16) ? (c0+r) : (1024 + c0 + (r-16));
      p = (const unsigned*)(wb + (size_t)row*Kst + kk + c*32);
    } else {
      const f16* ab = a ? Al : Ah;
      p = (const unsigned*)(ab + (size_t)(m0 + (r-32))*1024 + ak + c*32);
    }
    acc |= *p;
  }
  asm volatile("" :: "v"(acc) : "memory");
}

// ---- MFMA core: nch chunks of K=32; hi/lo compensated -------------------------
__device__ __forceinline__ void mm_core(
  const f16* __restrict__ Ap, const f16* __restrict__ Alp,
  const f16* __restrict__ Bg, const f16* __restrict__ Ba,
  const f16* __restrict__ Bgl, const f16* __restrict__ Bal,
  int nch, int wlo, float* __restrict__ Lg, float* __restrict__ La,
  int region, int q8, int l15)
{
  f32x4 g0={0,0,0,0},g1={0,0,0,0},a0={0,0,0,0},a1={0,0,0,0};
  #pragma unroll 2
  for (int c=0;c<nch;c++){
    int s = c*32;
    half8 ah=ldh8(Ap+s), al=ldh8(Alp+s);
    half8 wg=ldh8(Bg+s), wa=ldh8(Ba+s);
    g0=MFMA(ah,wg,g0); a0=MFMA(ah,wa,a0);
    g1=MFMA(al,wg,g1); a1=MFMA(al,wa,a1);
    if (wlo){ g1=MFMA(ah,ldh8(Bgl+s),g1); a1=MFMA(ah,ldh8(Bal+s),a1); }
  }
  f32x4 gg = g0 + g1*RLOSC, aa = a0 + a1*RLOSC;
  const int base = region*WSZ + (q8>>1)*RS + l15;   // row-in-tile = q*4+rr
  #pragma unroll
  for (int rr=0;rr<4;rr++){
    Lg[base + rr*RS] = gg[rr];
    La[base + rr*RS] = aa[rr];
  }
}

// ---- generic node slice: touch + matmul (K stride 1024 weights) ---------------
__device__ __forceinline__ void node_g(
  const f16* __restrict__ SHs, const f16* __restrict__ SLs,
  const f16* __restrict__ Wh, const f16* __restrict__ Wl,
  float* __restrict__ Lg, float* __restrict__ La,
  int region, int kk, int nch, int m0, int c0, int q8, int l15, int lane, int wlo)
{
  touch_tiles(Wh, Wl, 1024, c0, kk, SHs, SLs, m0, kk, nch, wlo, lane);
  const f16* Ap  = SHs + (m0+l15)*1024 + kk + q8;
  const f16* Alp = SLs + (m0+l15)*1024 + kk + q8;
  const f16* Bg  = Wh + (c0+l15)*1024 + kk + q8;
  const f16* Ba  = Wh + (1024+c0+l15)*1024 + kk + q8;
  const f16* Bgl = wlo ? Wl + (c0+l15)*1024 + kk + q8 : Bg;
  const f16* Bal = wlo ? Wl + (1024+c0+l15)*1024 + kk + q8 : Ba;
  mm_core(Ap,Alp,Bg,Ba,Bgl,Bal,nch,wlo,Lg,La,region,q8,l15);
}

// ---- reduce partials [r0, r0+nr), apply gate/act ------------------------------
__device__ __forceinline__ float fin_val(const float* __restrict__ Lg, const float* __restrict__ La,
  const float* __restrict__ ST, int t256, int m0, int c0, int r0, int nr, int sp, int actk)
{
  const int row = t256>>4, col = t256&15;
  const int e = row*RS + col;
  float gs=0.f, as=0.f;
  for (int r=r0; r<r0+nr; ++r){ gs += Lg[r*WSZ+e]; as += La[r*WSZ+e]; }
  float spv = ST[sp*65536 + (m0+row)*1024 + c0 + col];
  return spv + sgm(gs)*(applyact(actk,as)-spv);
}

__device__ __forceinline__ void fin_write(const float* __restrict__ Lg, const float* __restrict__ La,
  float* __restrict__ ST, f16* __restrict__ SH, f16* __restrict__ SL,
  int t256, int m0, int c0, int r0, int nr, int sp, int so, int actk, bool hl)
{
  float s = fin_val(Lg, La, ST, t256, m0, c0, r0, nr, sp, actk);
  const int row = t256>>4, col = t256&15;
  const int idx = so*65536 + (m0+row)*1024 + c0 + col;
  ST[idx] = s;
  if (hl){ f16 hi=(f16)s; SH[idx]=hi; SL[idx]=(f16)((s-(float)hi)*LOSC); }
}

// ------------------------------- persistent kernel ------------------------------
__global__ __launch_bounds__(1024,4) void darts_coop(
  const int* __restrict__ X, const float* __restrict__ emb,
  const float* __restrict__ Wout, const float* __restrict__ bout, float* __restrict__ out,
  const f16* __restrict__ W0Th, const f16* __restrict__ W0Tl,
  const f16* __restrict__ WsTh, const f16* __restrict__ WsTl,
  float* __restrict__ ST, f16* __restrict__ SH, f16* __restrict__ SL,
  f16* __restrict__ XNH, f16* __restrict__ XNL,
  unsigned* bar, int wlo)
{
  const int tid = threadIdx.x, b = blockIdx.x;
  const int wid = tid>>6, lane = tid&63, l15 = lane&15, q8 = (lane>>4)*8;
  // XCD swizzle: the 4 blocks sharing a weight stripe (same sct) land on one XCD.
  const int mt = (b>>3)&3, sct = (b&7)*8 + (b>>5);
  const int m0 = mt*16, c0 = sct*16;
  __shared__ float Lg[LSZ], La[LSZ];
  __shared__ float S6[256], S8[256];
  unsigned ph = 0;

  for (int t=0; t<TT; ++t){
    // ---- P0: node0 (A=[x|h], K=2048) + x(t+1) gather into alt buffer ----------
    if (t+1 < TT && tid < 256){
      int row = b>>2, col = ((b&3)<<8) + tid;
      int tok = X[(t+1)*64 + row];
      float v = emb[(size_t)tok*1024 + col];
      f16 hi=(f16)v;
      int xi = ((t+1)&1)*65536 + row*1024 + col;
      XNH[xi]=hi; XNL[xi]=(f16)((v-(float)hi)*LOSC);
    }
    {
      const f16* XH = XNH + (t&1)*65536;
      const f16* XL = XNL + (t&1)*65536;
      int kk = wid*128, ak = kk & 1023;
      const f16* Abh = (wid<8)? XH : SH;    // slot0 = h
      const f16* Abl = (wid<8)? XL : SL;
      touch_tiles(W0Th, W0Tl, 2048, c0, kk, Abh, Abl, m0, ak, 4, wlo, lane);
      const f16* Ap  = Abh + (m0+l15)*1024 + ak + q8;
      const f16* Alp = Abl + (m0+l15)*1024 + ak + q8;
      const f16* Bg  = W0Th + (c0+l15)*2048 + kk + q8;
      const f16* Ba  = W0Th + (1024+c0+l15)*2048 + kk + q8;
      const f16* Bgl = wlo ? W0Tl + (c0+l15)*2048 + kk + q8 : Bg;
      const f16* Bal = wlo ? W0Tl + (1024+c0+l15)*2048 + kk + q8 : Ba;
      mm_core(Ap,Alp,Bg,Ba,Bgl,Bal,4,wlo,Lg,La,wid,q8,l15);
    }
    __syncthreads();
    if (tid<256) fin_write(Lg,La,ST,SH,SL, tid, m0,c0, 0,16, /*sp*/0, /*out*/1, /*tanh*/0, true);
    gbar(bar, ph++, b, wid, lane);

    // ---- P1: node1 (pred s0=slot1, Ws[0], sigmoid), 16 waves, K=1024 ----------
    node_g(SH+1*65536, SL+1*65536, WsTh, WsTl, Lg, La, wid, wid*64, 2, m0,c0,q8,l15,lane,wlo);
    __syncthreads();
    if (tid<256) fin_write(Lg,La,ST,SH,SL, tid, m0,c0, 0,16, 1, 2, /*sigmoid*/1, true);
    gbar(bar, ph++, b, wid, lane);

    // ---- P2: n2 (waves 0-7) || n3 (waves 8-15), both pred s1=slot2, relu ------
    if (wid<8)
      node_g(SH+2*65536, SL+2*65536, WsTh+(size_t)1*2097152,
             wlo? WsTl+(size_t)1*2097152 : (const f16*)0,
             Lg, La, wid, wid*128, 4, m0,c0,q8,l15,lane,wlo);
    else
      node_g(SH+2*65536, SL+2*65536, WsTh+(size_t)2*2097152,
             wlo? WsTl+(size_t)2*2097152 : (const f16*)0,
             Lg, La, wid, (wid-8)*128, 4, m0,c0,q8,l15,lane,wlo);
    __syncthreads();
    if (tid<256)      fin_write(Lg,La,ST,SH,SL, tid,     m0,c0, 0,8, 2, 3, /*relu*/2, true);
    else if (tid<512) fin_write(Lg,La,ST,SH,SL, tid-256, m0,c0, 8,8, 2, 4, /*relu*/2, true);
    gbar(bar, ph++, b, wid, lane);

    // ---- P3: n5 (wid 0-4, pred s2=slot3) || n7 (wid 5-9, pred s3=slot4)
    //          || n4 (wid 10-15, pred s1=slot2, identity) ----------------------
    if (wid < 5){
      int i = wid;    int s=(i*32)/5, e=((i+1)*32)/5;
      node_g(SH+3*65536, SL+3*65536, WsTh+(size_t)4*2097152,
             wlo? WsTl+(size_t)4*2097152 : (const f16*)0,
             Lg, La, wid, s*32, e-s, m0,c0,q8,l15,lane,wlo);
    } else if (wid < 10){
      int i = wid-5;  int s=(i*32)/5, e=((i+1)*32)/5;
      node_g(SH+4*65536, SL+4*65536, WsTh+(size_t)6*2097152,
             wlo? WsTl+(size_t)6*2097152 : (const f16*)0,
             Lg, La, wid, s*32, e-s, m0,c0,q8,l15,lane,wlo);
    } else {
      int i = wid-10; int s=(i*32)/6, e=((i+1)*32)/6;
      node_g(SH+2*65536, SL+2*65536, WsTh+(size_t)3*2097152,
             wlo? WsTl+(size_t)3*2097152 : (const f16*)0,
             Lg, La, wid, s*32, e-s, m0,c0,q8,l15,lane,wlo);
    }
    __syncthreads();
    if (tid<256)      fin_write(Lg,La,ST,SH,SL, tid,     m0,c0, 0,5,  3, 6, /*tanh*/0, true);
    else if (tid<512) fin_write(Lg,La,ST,SH,SL, tid-256, m0,c0, 5,5,  4, 8, /*tanh*/0, false);
    else if (tid<768) fin_write(Lg,La,ST,SH,SL, tid-512, m0,c0, 10,6, 2, 5, /*ident*/3, false);
    gbar(bar, ph++, b, wid, lane);

    // ---- P4: n6 (sigmoid) || n8 (relu), both pred s5=slot6; mean -> h ---------
    if (wid<8)
      node_g(SH+6*65536, SL+6*65536, WsTh+(size_t)5*2097152,
             wlo? WsTl+(size_t)5*2097152 : (const f16*)0,
             Lg, La, wid, wid*128, 4, m0,c0,q8,l15,lane,wlo);
    else
      node_g(SH+6*65536, SL+6*65536, WsTh+(size_t)7*2097152,
             wlo? WsTl+(size_t)7*2097152 : (const f16*)0,
             Lg, La, wid, (wid-8)*128, 4, m0,c0,q8,l15,lane,wlo);
    __syncthreads();
    if (tid<256)      S6[tid]     = fin_val(Lg,La,ST, tid,     m0,c0, 0,8, 6, /*sigmoid*/1);
    else if (tid<512) S8[tid-256] = fin_val(Lg,La,ST, tid-256, m0,c0, 8,8, 6, /*relu*/2);
    __syncthreads();
    if (tid<256){
      const int row = tid>>4, col = tid&15;
      const int idx = (m0+row)*1024 + c0 + col;
      float m = (ST[2*65536+idx]+ST[3*65536+idx]+ST[4*65536+idx]+ST[5*65536+idx]
               + ST[6*65536+idx]+ST[8*65536+idx]+S6[tid]+S8[tid])*0.125f;
      ST[idx]=m;
      f16 hi=(f16)m; SH[idx]=hi; SL[idx]=(f16)((m-(float)hi)*LOSC);
    }
    gbar(bar, ph++, b, wid, lane);
  }

  // ---- final head: a_hat = h @ Wout + bout ; probs = softmax --------------------
  if (b==0 && tid<256){
    int row = tid>>2, col = tid&3;
    float acc = bout[col];
    const float* hrow = ST + row*1024;
    #pragma unroll 8
    for (int k=0;k<1024;k++) acc += hrow[k]*Wout[k*4+col];
    out[row*4+col] = acc;
    float m = fmaxf(acc, __shfl_xor(acc,1));
    m = fmaxf(m, __shfl_xor(m,2));
    float e = __expf(acc-m);
    float ssum = e + __shfl_xor(e,1);
    ssum = ssum + __shfl_xor(ssum,2);
    out[256 + row*4+col] = e/ssum;
  }
}

// ------------------------------- prep kernels -----------------------------------
__global__ void prep_x0(const int* __restrict__ X, const float* __restrict__ hidden,
  const float* __restrict__ emb, f16* __restrict__ XNH, f16* __restrict__ XNL,
  float* __restrict__ ST, f16* __restrict__ SH, f16* __restrict__ SL, unsigned* bar)
{
  int idx = blockIdx.x*256 + threadIdx.x;   // 65536 threads
  float hv = hidden[idx];
  ST[idx] = hv;
  f16 hh=(f16)hv; SH[idx]=hh; SL[idx]=(f16)((hv-(float)hh)*LOSC);
  int brow = idx>>10, k = idx&1023;
  int tok = X[brow];
  float v = emb[tok*1024+k];
  f16 xh=(f16)v; XNH[idx]=xh; XNL[idx]=(f16)((v-(float)xh)*LOSC);  // slot 0 (t=0)
  if (idx < 4096) bar[idx] = 0u;
}

__global__ void prep_w(const float* __restrict__ W0, const float* __restrict__ Ws,
  f16* __restrict__ W0Th, f16* __restrict__ W0Tl, f16* __restrict__ WsTh, f16* __restrict__ WsTl)
{
  __shared__ float L[64][65];
  int b = blockIdx.x, tid = threadIdx.x;
  const float* src; f16 *Dh, *Dl; int K, tk, tn;
  if (b < 1024){ src=W0; Dh=W0Th; Dl=W0Tl; K=2048; tk=b&31; tn=b>>5; }
  else { int bb=b-1024; int mi=bb>>9; int t2=bb&511; tk=t2&15; tn=t2>>4;
         src = Ws + (size_t)mi*1024*2048; Dh = WsTh + (size_t)mi*2097152;
         Dl = WsTl ? (WsTl + (size_t)mi*2097152) : (f16*)0; K=1024; }
  int k0 = tk*64, n0 = tn*64;
  int rr = tid>>6, cc = tid&63;
  #pragma unroll
  for (int j=0;j<16;j++){
    int r = j*4 + rr;
    L[cc][r] = src[(size_t)(k0+r)*2048 + n0+cc];
  }
  __syncthreads();
  #pragma unroll
  for (int j=0;j<16;j++){
    int n = j*4 + rr;
    float v = L[n][cc];
    f16 hi = (f16)v;
    Dh[(size_t)(n0+n)*K + k0+cc] = hi;
    if (Dl) Dl[(size_t)(n0+n)*K + k0+cc] = (f16)((v-(float)hi)*LOSC);
  }
}

__global__ void sentinel_k(float* __restrict__ out, float v){
  int i = blockIdx.x*256 + threadIdx.x;
  if (i < 512) out[i] = v;
}

// ------------------------------- launcher ----------------------------------------
extern "C" void kernel_launch(void* const* d_in, const int* in_sizes, int n_in,
                              void* d_out, int out_size, void* d_ws, size_t ws_size,
                              hipStream_t stream)
{
  const int*   X      = (const int*)  d_in[0];
  const float* hidden = (const float*)d_in[1];
  const float* emb    = (const float*)d_in[2];
  const float* W0     = (const float*)d_in[3];
  const float* Ws     = (const float*)d_in[4];
  const float* Wout   = (const float*)d_in[5];
  const float* bout   = (const float*)d_in[6];
  float* out = (float*)d_out;

  const size_t SZ_W0   = (size_t)2048*2048*2;      // 8.39 MB (f16)
  const size_t SZ_WS   = (size_t)8*2048*1024*2;    // 33.55 MB
  const size_t SZ_ST   = (size_t)10*65536*4;
  const size_t SZ_SHL  = (size_t)10*65536*2;
  const size_t SZ_XN   = (size_t)2*65536*2;        // double-buffered
  const size_t SZ_BAR  = 16384;

  auto pad = [](size_t x){ return (x + 255) & ~(size_t)255; };
  size_t need_red  = pad(SZ_W0) + pad(SZ_WS) + pad(SZ_ST) + 2*pad(SZ_SHL)
                   + 2*pad(SZ_XN) + pad(SZ_BAR);
  size_t need_full = need_red + pad(SZ_W0) + pad(SZ_WS);

  int wlo;
  if (ws_size >= need_full)      wlo = 1;
  else if (ws_size >= need_red)  wlo = 0;
  else { hipLaunchKernelGGL(sentinel_k, dim3(2), dim3(256), 0, stream, out, 1.0e6f); return; }

  char* w = (char*)d_ws; size_t off = 0;
  auto alloc = [&](size_t bytes)->void*{ void* p = w+off; off += (bytes+255)&~(size_t)255; return p; };
  f16* W0Th = (f16*)alloc(SZ_W0);
  f16* WsTh = (f16*)alloc(SZ_WS);
  f16* W0Tl = wlo ? (f16*)alloc(SZ_W0) : (f16*)0;
  f16* WsTl = wlo ? (f16*)alloc(SZ_WS) : (f16*)0;
  float* ST = (float*)alloc(SZ_ST);
  f16* SH   = (f16*)alloc(SZ_SHL);
  f16* SL   = (f16*)alloc(SZ_SHL);
  f16* XNH  = (f16*)alloc(SZ_XN);
  f16* XNL  = (f16*)alloc(SZ_XN);
  unsigned* bar = (unsigned*)alloc(SZ_BAR);

  hipLaunchKernelGGL(prep_x0, dim3(256), dim3(256), 0, stream,
                     X, hidden, emb, XNH, XNL, ST, SH, SL, bar);
  hipLaunchKernelGGL(prep_w, dim3(5120), dim3(256), 0, stream,
                     W0, Ws, W0Th, W0Tl, WsTh, WsTl);

  // 256 blocks x 1024 threads: 1 block/CU -> co-residency guaranteed.
  void* args[] = { (void*)&X, (void*)&emb, (void*)&Wout, (void*)&bout, (void*)&out,
                   (void*)&W0Th, (void*)&W0Tl, (void*)&WsTh, (void*)&WsTl,
                   (void*)&ST, (void*)&SH, (void*)&SL, (void*)&XNH, (void*)&XNL,
                   (void*)&bar, (void*)&wlo };
  hipError_t e = hipLaunchCooperativeKernel((void*)darts_coop, dim3(256), dim3(1024), args, 0, stream);
  if (e != hipSuccess){
    hipLaunchKernelGGL(darts_coop, dim3(256), dim3(1024), 0, stream,
                       X, emb, Wout, bout, out, W0Th, W0Tl, WsTh, WsTl,
                       ST, SH, SL, XNH, XNL, bar, wlo);
  }
}

// Round 4
// 64887.909 us; speedup vs baseline: 1.2154x; 1.2154x over previous
//
#include <hip/hip_runtime.h>

#define TT 512

typedef _Float16 f16;
typedef _Float16 half8 __attribute__((ext_vector_type(8)));
typedef float f32x4 __attribute__((ext_vector_type(4)));

#define MFMA(a,b,c) __builtin_amdgcn_mfma_f32_16x16x32_f16((a),(b),(c),0,0,0)
#define LOSC  2048.0f
#define RLOSC 0.00048828125f   // 1/2048

// LDS partial layout: per-wave region of 16 rows, row stride 18 floats.
#define RS  18
#define WSZ (16*RS)      // 288 floats per wave region
#define LSZ (16*WSZ)     // 4608 floats per buffer (18.4 KB)

__device__ __forceinline__ half8 ldh8(const f16* p){ return *(const half8*)p; }
__device__ __forceinline__ float sgm(float x){ return 1.f/(1.f+__expf(-x)); }
// act kinds: 0 tanh, 1 sigmoid, 2 relu, 3 identity
__device__ __forceinline__ float applyact(int k, float x){
  if (k==0) return tanhf(x);
  if (k==1) return sgm(x);
  if (k==2) return fmaxf(x,0.f);
  return x;
}

// ---- grid barrier v3: private slots + single-block detect + broadcast flag ----
// Each block stores phase count to its own 64B-aligned slot (bar[b*16]).
// Block 0's first 256 threads each poll ONE slot; then tid0 publishes bar[4096].
// All blocks poll the single broadcast word. No RMW, no all-to-all scan.
__device__ __forceinline__ void gbar_arrive(unsigned* bar, unsigned ph, int b, int tid){
  __syncthreads();
  if (tid==0){
    __builtin_amdgcn_fence(__ATOMIC_RELEASE, "agent");
    __hip_atomic_store(&bar[b*16], ph+1u, __ATOMIC_RELAXED, __HIP_MEMORY_SCOPE_AGENT);
  }
}

__device__ __forceinline__ void gbar_wait(unsigned* bar, unsigned ph, int b, int tid){
  const unsigned tgt = ph + 1u;
  if (b==0){
    if (tid<256){
      while (__hip_atomic_load(&bar[tid*16], __ATOMIC_RELAXED, __HIP_MEMORY_SCOPE_AGENT) < tgt)
        __builtin_amdgcn_s_sleep(2);
    }
    __syncthreads();
    if (tid==0){
      __builtin_amdgcn_fence(__ATOMIC_ACQ_REL, "agent");   // transitivity pivot
      __hip_atomic_store(&bar[4096], tgt, __ATOMIC_RELAXED, __HIP_MEMORY_SCOPE_AGENT);
    }
  }
  if (tid==0){
    while (__hip_atomic_load(&bar[4096], __ATOMIC_RELAXED, __HIP_MEMORY_SCOPE_AGENT) < tgt)
      __builtin_amdgcn_s_sleep(2);
    __builtin_amdgcn_fence(__ATOMIC_ACQUIRE, "agent");
  }
  __syncthreads();
}

// ---- preloaded weight fragment: 2 K-chunks (g,a)x(hi,lo) = 8 half8 = 32 VGPR --
// Weights are CONSTANT -> legal to load before the acquire fence; the loads fly
// during the barrier wait and survive the L2 invalidate in registers.
struct WF2 { half8 g0,a0,gl0,al0,g1,a1,gl1,al1; };

__device__ __forceinline__ WF2 preW(const f16* __restrict__ Wh, const f16* __restrict__ Wl,
  int Kst, int c0, int kk, int q8, int l15, int wlo)
{
  WF2 F;
  const f16* Bg = Wh + (size_t)(c0+l15)*Kst + kk + q8;
  const f16* Ba = Wh + (size_t)(1024+c0+l15)*Kst + kk + q8;
  F.g0=ldh8(Bg); F.a0=ldh8(Ba); F.g1=ldh8(Bg+32); F.a1=ldh8(Ba+32);
  if (wlo){
    const f16* Bgl = Wl + (size_t)(c0+l15)*Kst + kk + q8;
    const f16* Bal = Wl + (size_t)(1024+c0+l15)*Kst + kk + q8;
    F.gl0=ldh8(Bgl); F.al0=ldh8(Bal); F.gl1=ldh8(Bgl+32); F.al1=ldh8(Bal+32);
  } else { F.gl0=F.g0; F.al0=F.a0; F.gl1=F.g1; F.al1=F.a1; }
  return F;
}

// ---- MFMA core: chunks 0-1 from preloaded F, chunks 2..NCH-1 loaded in-loop ---
template<int NCH>
__device__ __forceinline__ void mm_mix(const WF2& F,
  const f16* __restrict__ Ap, const f16* __restrict__ Alp,
  const f16* __restrict__ Bg, const f16* __restrict__ Ba,
  const f16* __restrict__ Bgl, const f16* __restrict__ Bal,
  int wlo, float* __restrict__ Lg, float* __restrict__ La,
  int region, int q8, int l15)
{
  f32x4 g0={0,0,0,0},g1={0,0,0,0},a0={0,0,0,0},a1={0,0,0,0};
  {
    half8 ah=ldh8(Ap), al=ldh8(Alp);
    g0=MFMA(ah,F.g0,g0); a0=MFMA(ah,F.a0,a0);
    g1=MFMA(al,F.g0,g1); a1=MFMA(al,F.a0,a1);
    if (wlo){ g1=MFMA(ah,F.gl0,g1); a1=MFMA(ah,F.al0,a1); }
  }
  if (NCH>1){
    half8 ah=ldh8(Ap+32), al=ldh8(Alp+32);
    g0=MFMA(ah,F.g1,g0); a0=MFMA(ah,F.a1,a0);
    g1=MFMA(al,F.g1,g1); a1=MFMA(al,F.a1,a1);
    if (wlo){ g1=MFMA(ah,F.gl1,g1); a1=MFMA(ah,F.al1,a1); }
  }
  #pragma unroll
  for (int c=2;c<NCH;c++){
    int s=c*32;
    half8 ah=ldh8(Ap+s), al=ldh8(Alp+s);
    half8 wg=ldh8(Bg+s), wa=ldh8(Ba+s);
    g0=MFMA(ah,wg,g0); a0=MFMA(ah,wa,a0);
    g1=MFMA(al,wg,g1); a1=MFMA(al,wa,a1);
    if (wlo){ g1=MFMA(ah,ldh8(Bgl+s),g1); a1=MFMA(ah,ldh8(Bal+s),a1); }
  }
  f32x4 gg = g0 + g1*RLOSC, aa = a0 + a1*RLOSC;
  const int base = region*WSZ + (q8>>1)*RS + l15;   // row-in-tile = q*4+rr
  #pragma unroll
  for (int rr=0;rr<4;rr++){
    Lg[base + rr*RS] = gg[rr];
    La[base + rr*RS] = aa[rr];
  }
}

// ---- standard node with preloaded fragment (K stride 1024 weights) ------------
template<int NCH>
__device__ __forceinline__ void node_pre(const WF2& F,
  const f16* __restrict__ SHs, const f16* __restrict__ SLs,
  const f16* __restrict__ Wh, const f16* __restrict__ Wl,
  float* __restrict__ Lg, float* __restrict__ La,
  int region, int kk, int m0, int c0, int q8, int l15, int wlo)
{
  const f16* Ap  = SHs + (m0+l15)*1024 + kk + q8;
  const f16* Alp = SLs + (m0+l15)*1024 + kk + q8;
  const f16* Bg  = Wh + (size_t)(c0+l15)*1024 + kk + q8;
  const f16* Ba  = Wh + (size_t)(1024+c0+l15)*1024 + kk + q8;
  const f16* Bgl = wlo ? Wl + (size_t)(c0+l15)*1024 + kk + q8 : Bg;
  const f16* Bal = wlo ? Wl + (size_t)(1024+c0+l15)*1024 + kk + q8 : Ba;
  mm_mix<NCH>(F, Ap, Alp, Bg, Ba, Bgl, Bal, wlo, Lg, La, region, q8, l15);
}

// ---- reduce partials [r0, r0+nr), apply gate/act ------------------------------
__device__ __forceinline__ float fin_val(const float* __restrict__ Lg, const float* __restrict__ La,
  const float* __restrict__ ST, int t256, int m0, int c0, int r0, int nr, int sp, int actk)
{
  const int row = t256>>4, col = t256&15;
  const int e = row*RS + col;
  float gs=0.f, as=0.f;
  for (int r=r0; r<r0+nr; ++r){ gs += Lg[r*WSZ+e]; as += La[r*WSZ+e]; }
  float spv = ST[sp*65536 + (m0+row)*1024 + c0 + col];
  return spv + sgm(gs)*(applyact(actk,as)-spv);
}

__device__ __forceinline__ void fin_write(const float* __restrict__ Lg, const float* __restrict__ La,
  float* __restrict__ ST, f16* __restrict__ SH, f16* __restrict__ SL,
  int t256, int m0, int c0, int r0, int nr, int sp, int so, int actk, bool hl)
{
  float s = fin_val(Lg, La, ST, t256, m0, c0, r0, nr, sp, actk);
  const int row = t256>>4, col = t256&15;
  const int idx = so*65536 + (m0+row)*1024 + c0 + col;
  ST[idx] = s;
  if (hl){ f16 hi=(f16)s; SH[idx]=hi; SL[idx]=(f16)((s-(float)hi)*LOSC); }
}

// ------------------------------- persistent kernel ------------------------------
__global__ __launch_bounds__(1024,4) void darts_coop(
  const int* __restrict__ X, const float* __restrict__ emb,
  const float* __restrict__ Wout, const float* __restrict__ bout, float* __restrict__ out,
  const f16* __restrict__ W0Th, const f16* __restrict__ W0Tl,
  const f16* __restrict__ WsTh, const f16* __restrict__ WsTl,
  float* __restrict__ ST, f16* __restrict__ SH, f16* __restrict__ SL,
  f16* __restrict__ XNH, f16* __restrict__ XNL,
  unsigned* bar, int wlo)
{
  const int tid = threadIdx.x, b = blockIdx.x;
  const int wid = tid>>6, lane = tid&63, l15 = lane&15, q8 = (lane>>4)*8;
  // XCD swizzle: the 4 blocks sharing a weight stripe (same sct) land on one XCD.
  const int mt = (b>>3)&3, sct = (b&7)*8 + (b>>5);
  const int m0 = mt*16, c0 = sct*16;
  __shared__ float Lg[LSZ], La[LSZ];
  __shared__ float S6[256], S8[256];
  unsigned ph = 0;

  // preload P0 (t=0) weights
  WF2 F0 = preW(W0Th, W0Tl, 2048, c0, wid*128, q8, l15, wlo);

  for (int t=0; t<TT; ++t){
    // ---- P0: node0 (A=[x|h], K=2048) + x(t+1) gather into alt buffer ----------
    if (t+1 < TT && tid < 256){
      int row = b>>2, col = ((b&3)<<8) + tid;
      int tok = X[(t+1)*64 + row];
      float v = emb[(size_t)tok*1024 + col];
      f16 hi=(f16)v;
      int xi = ((t+1)&1)*65536 + row*1024 + col;
      XNH[xi]=hi; XNL[xi]=(f16)((v-(float)hi)*LOSC);
    }
    {
      const f16* XH = XNH + (t&1)*65536;
      const f16* XL = XNL + (t&1)*65536;
      int kk = wid*128, ak = kk & 1023;
      const f16* Abh = (wid<8)? XH : SH;    // slot0 = h
      const f16* Abl = (wid<8)? XL : SL;
      const f16* Ap  = Abh + (m0+l15)*1024 + ak + q8;
      const f16* Alp = Abl + (m0+l15)*1024 + ak + q8;
      const f16* Bg  = W0Th + (size_t)(c0+l15)*2048 + kk + q8;
      const f16* Ba  = W0Th + (size_t)(1024+c0+l15)*2048 + kk + q8;
      const f16* Bgl = wlo ? W0Tl + (size_t)(c0+l15)*2048 + kk + q8 : Bg;
      const f16* Bal = wlo ? W0Tl + (size_t)(1024+c0+l15)*2048 + kk + q8 : Ba;
      mm_mix<4>(F0, Ap, Alp, Bg, Ba, Bgl, Bal, wlo, Lg, La, wid, q8, l15);
    }
    __syncthreads();
    if (tid<256) fin_write(Lg,La,ST,SH,SL, tid, m0,c0, 0,16, /*sp*/0, /*out*/1, /*tanh*/0, true);
    gbar_arrive(bar, ph, b, tid);
    WF2 F1 = preW(WsTh, WsTl, 1024, c0, wid*64, q8, l15, wlo);          // node1 W
    gbar_wait(bar, ph, b, tid); ph++;

    // ---- P1: node1 (pred s0=slot1, Ws[0], sigmoid), 16 waves, K=1024 ----------
    node_pre<2>(F1, SH+1*65536, SL+1*65536, WsTh, WsTl, Lg, La, wid, wid*64, m0,c0,q8,l15,wlo);
    __syncthreads();
    if (tid<256) fin_write(Lg,La,ST,SH,SL, tid, m0,c0, 0,16, 1, 2, /*sigmoid*/1, true);
    gbar_arrive(bar, ph, b, tid);
    WF2 F2 = (wid<8)
      ? preW(WsTh+(size_t)1*2097152, wlo? WsTl+(size_t)1*2097152 : (const f16*)0,
             1024, c0, (wid&7)*128, q8, l15, wlo)
      : preW(WsTh+(size_t)2*2097152, wlo? WsTl+(size_t)2*2097152 : (const f16*)0,
             1024, c0, (wid&7)*128, q8, l15, wlo);
    gbar_wait(bar, ph, b, tid); ph++;

    // ---- P2a: n2 (waves 0-7) || n3 (waves 8-15), both pred s1=slot2, relu -----
    if (wid<8)
      node_pre<4>(F2, SH+2*65536, SL+2*65536, WsTh+(size_t)1*2097152,
                  wlo? WsTl+(size_t)1*2097152 : (const f16*)0,
                  Lg, La, wid, (wid&7)*128, m0,c0,q8,l15,wlo);
    else
      node_pre<4>(F2, SH+2*65536, SL+2*65536, WsTh+(size_t)2*2097152,
                  wlo? WsTl+(size_t)2*2097152 : (const f16*)0,
                  Lg, La, wid, (wid&7)*128, m0,c0,q8,l15,wlo);
    __syncthreads();
    if (tid<256)      fin_write(Lg,La,ST,SH,SL, tid,     m0,c0, 0,8, 2, 3, /*relu*/2, true);
    else if (tid<512) fin_write(Lg,La,ST,SH,SL, tid-256, m0,c0, 8,8, 2, 4, /*relu*/2, true);
    __syncthreads();

    // ---- P2b: n4 (identity, pred s1), 16 waves, K=1024 (A warm from P2a) ------
    {
      WF2 F2b = preW(WsTh+(size_t)3*2097152, wlo? WsTl+(size_t)3*2097152 : (const f16*)0,
                     1024, c0, wid*64, q8, l15, wlo);
      node_pre<2>(F2b, SH+2*65536, SL+2*65536, WsTh+(size_t)3*2097152,
                  wlo? WsTl+(size_t)3*2097152 : (const f16*)0,
                  Lg, La, wid, wid*64, m0,c0,q8,l15,wlo);
    }
    __syncthreads();
    if (tid<256) fin_write(Lg,La,ST,SH,SL, tid, m0,c0, 0,16, 2, 5, /*identity*/3, false);
    gbar_arrive(bar, ph, b, tid);
    WF2 F3 = (wid<8)
      ? preW(WsTh+(size_t)4*2097152, wlo? WsTl+(size_t)4*2097152 : (const f16*)0,
             1024, c0, (wid&7)*128, q8, l15, wlo)
      : preW(WsTh+(size_t)6*2097152, wlo? WsTl+(size_t)6*2097152 : (const f16*)0,
             1024, c0, (wid&7)*128, q8, l15, wlo);
    gbar_wait(bar, ph, b, tid); ph++;

    // ---- P3: n5 (pred s2=slot3, tanh) || n7 (pred s3=slot4, tanh) -------------
    if (wid<8)
      node_pre<4>(F3, SH+3*65536, SL+3*65536, WsTh+(size_t)4*2097152,
                  wlo? WsTl+(size_t)4*2097152 : (const f16*)0,
                  Lg, La, wid, (wid&7)*128, m0,c0,q8,l15,wlo);
    else
      node_pre<4>(F3, SH+4*65536, SL+4*65536, WsTh+(size_t)6*2097152,
                  wlo? WsTl+(size_t)6*2097152 : (const f16*)0,
                  Lg, La, wid, (wid&7)*128, m0,c0,q8,l15,wlo);
    __syncthreads();
    if (tid<256)      fin_write(Lg,La,ST,SH,SL, tid,     m0,c0, 0,8, 3, 6, /*tanh*/0, true);
    else if (tid<512) fin_write(Lg,La,ST,SH,SL, tid-256, m0,c0, 8,8, 4, 8, /*tanh*/0, false);
    gbar_arrive(bar, ph, b, tid);
    WF2 F4 = (wid<8)
      ? preW(WsTh+(size_t)5*2097152, wlo? WsTl+(size_t)5*2097152 : (const f16*)0,
             1024, c0, (wid&7)*128, q8, l15, wlo)
      : preW(WsTh+(size_t)7*2097152, wlo? WsTl+(size_t)7*2097152 : (const f16*)0,
             1024, c0, (wid&7)*128, q8, l15, wlo);
    gbar_wait(bar, ph, b, tid); ph++;

    // ---- P4: n6 (sigmoid) || n8 (relu), both pred s5=slot6; mean -> h ---------
    if (wid<8)
      node_pre<4>(F4, SH+6*65536, SL+6*65536, WsTh+(size_t)5*2097152,
                  wlo? WsTl+(size_t)5*2097152 : (const f16*)0,
                  Lg, La, wid, (wid&7)*128, m0,c0,q8,l15,wlo);
    else
      node_pre<4>(F4, SH+6*65536, SL+6*65536, WsTh+(size_t)7*2097152,
                  wlo? WsTl+(size_t)7*2097152 : (const f16*)0,
                  Lg, La, wid, (wid&7)*128, m0,c0,q8,l15,wlo);
    __syncthreads();
    if (tid<256)      S6[tid]     = fin_val(Lg,La,ST, tid,     m0,c0, 0,8, 6, /*sigmoid*/1);
    else if (tid<512) S8[tid-256] = fin_val(Lg,La,ST, tid-256, m0,c0, 8,8, 6, /*relu*/2);
    __syncthreads();
    if (tid<256){
      const int row = tid>>4, col = tid&15;
      const int idx = (m0+row)*1024 + c0 + col;
      float m = (ST[2*65536+idx]+ST[3*65536+idx]+ST[4*65536+idx]+ST[5*65536+idx]
               + ST[6*65536+idx]+ST[8*65536+idx]+S6[tid]+S8[tid])*0.125f;
      ST[idx]=m;
      f16 hi=(f16)m; SH[idx]=hi; SL[idx]=(f16)((m-(float)hi)*LOSC);
    }
    gbar_arrive(bar, ph, b, tid);
    F0 = preW(W0Th, W0Tl, 2048, c0, wid*128, q8, l15, wlo);   // next-step P0 W
    gbar_wait(bar, ph, b, tid); ph++;
  }

  // ---- final head: a_hat = h @ Wout + bout ; probs = softmax --------------------
  if (b==0 && tid<256){
    int row = tid>>2, col = tid&3;
    float acc = bout[col];
    const float* hrow = ST + row*1024;
    #pragma unroll 8
    for (int k=0;k<1024;k++) acc += hrow[k]*Wout[k*4+col];
    out[row*4+col] = acc;
    float m = fmaxf(acc, __shfl_xor(acc,1));
    m = fmaxf(m, __shfl_xor(m,2));
    float e = __expf(acc-m);
    float ssum = e + __shfl_xor(e,1);
    ssum = ssum + __shfl_xor(ssum,2);
    out[256 + row*4+col] = e/ssum;
  }
}

// ------------------------------- prep kernels -----------------------------------
__global__ void prep_x0(const int* __restrict__ X, const float* __restrict__ hidden,
  const float* __restrict__ emb, f16* __restrict__ XNH, f16* __restrict__ XNL,
  float* __restrict__ ST, f16* __restrict__ SH, f16* __restrict__ SL, unsigned* bar)
{
  int idx = blockIdx.x*256 + threadIdx.x;   // 65536 threads
  float hv = hidden[idx];
  ST[idx] = hv;
  f16 hh=(f16)hv; SH[idx]=hh; SL[idx]=(f16)((hv-(float)hh)*LOSC);
  int brow = idx>>10, k = idx&1023;
  int tok = X[brow];
  float v = emb[tok*1024+k];
  f16 xh=(f16)v; XNH[idx]=xh; XNL[idx]=(f16)((v-(float)xh)*LOSC);  // slot 0 (t=0)
  if (idx < 8192) bar[idx] = 0u;
}

__global__ void prep_w(const float* __restrict__ W0, const float* __restrict__ Ws,
  f16* __restrict__ W0Th, f16* __restrict__ W0Tl, f16* __restrict__ WsTh, f16* __restrict__ WsTl)
{
  __shared__ float L[64][65];
  int b = blockIdx.x, tid = threadIdx.x;
  const float* src; f16 *Dh, *Dl; int K, tk, tn;
  if (b < 1024){ src=W0; Dh=W0Th; Dl=W0Tl; K=2048; tk=b&31; tn=b>>5; }
  else { int bb=b-1024; int mi=bb>>9; int t2=bb&511; tk=t2&15; tn=t2>>4;
         src = Ws + (size_t)mi*1024*2048; Dh = WsTh + (size_t)mi*2097152;
         Dl = WsTl ? (WsTl + (size_t)mi*2097152) : (f16*)0; K=1024; }
  int k0 = tk*64, n0 = tn*64;
  int rr = tid>>6, cc = tid&63;
  #pragma unroll
  for (int j=0;j<16;j++){
    int r = j*4 + rr;
    L[cc][r] = src[(size_t)(k0+r)*2048 + n0+cc];
  }
  __syncthreads();
  #pragma unroll
  for (int j=0;j<16;j++){
    int n = j*4 + rr;
    float v = L[n][cc];
    f16 hi = (f16)v;
    Dh[(size_t)(n0+n)*K + k0+cc] = hi;
    if (Dl) Dl[(size_t)(n0+n)*K + k0+cc] = (f16)((v-(float)hi)*LOSC);
  }
}

__global__ void sentinel_k(float* __restrict__ out, float v){
  int i = blockIdx.x*256 + threadIdx.x;
  if (i < 512) out[i] = v;
}

// ------------------------------- launcher ----------------------------------------
extern "C" void kernel_launch(void* const* d_in, const int* in_sizes, int n_in,
                              void* d_out, int out_size, void* d_ws, size_t ws_size,
                              hipStream_t stream)
{
  const int*   X      = (const int*)  d_in[0];
  const float* hidden = (const float*)d_in[1];
  const float* emb    = (const float*)d_in[2];
  const float* W0     = (const float*)d_in[3];
  const float* Ws     = (const float*)d_in[4];
  const float* Wout   = (const float*)d_in[5];
  const float* bout   = (const float*)d_in[6];
  float* out = (float*)d_out;

  const size_t SZ_W0   = (size_t)2048*2048*2;      // 8.39 MB (f16)
  const size_t SZ_WS   = (size_t)8*2048*1024*2;    // 33.55 MB
  const size_t SZ_ST   = (size_t)10*65536*4;
  const size_t SZ_SHL  = (size_t)10*65536*2;
  const size_t SZ_XN   = (size_t)2*65536*2;        // double-buffered
  const size_t SZ_BAR  = 32768;

  auto pad = [](size_t x){ return (x + 255) & ~(size_t)255; };
  size_t need_red  = pad(SZ_W0) + pad(SZ_WS) + pad(SZ_ST) + 2*pad(SZ_SHL)
                   + 2*pad(SZ_XN) + pad(SZ_BAR);
  size_t need_full = need_red + pad(SZ_W0) + pad(SZ_WS);

  int wlo;
  if (ws_size >= need_full)      wlo = 1;
  else if (ws_size >= need_red)  wlo = 0;
  else { hipLaunchKernelGGL(sentinel_k, dim3(2), dim3(256), 0, stream, out, 1.0e6f); return; }

  char* w = (char*)d_ws; size_t off = 0;
  auto alloc = [&](size_t bytes)->void*{ void* p = w+off; off += (bytes+255)&~(size_t)255; return p; };
  f16* W0Th = (f16*)alloc(SZ_W0);
  f16* WsTh = (f16*)alloc(SZ_WS);
  f16* W0Tl = wlo ? (f16*)alloc(SZ_W0) : (f16*)0;
  f16* WsTl = wlo ? (f16*)alloc(SZ_WS) : (f16*)0;
  float* ST = (float*)alloc(SZ_ST);
  f16* SH   = (f16*)alloc(SZ_SHL);
  f16* SL   = (f16*)alloc(SZ_SHL);
  f16* XNH  = (f16*)alloc(SZ_XN);
  f16* XNL  = (f16*)alloc(SZ_XN);
  unsigned* bar = (unsigned*)alloc(SZ_BAR);

  hipLaunchKernelGGL(prep_x0, dim3(256), dim3(256), 0, stream,
                     X, hidden, emb, XNH, XNL, ST, SH, SL, bar);
  hipLaunchKernelGGL(prep_w, dim3(5120), dim3(256), 0, stream,
                     W0, Ws, W0Th, W0Tl, WsTh, WsTl);

  // 256 blocks x 1024 threads: 1 block/CU -> co-residency guaranteed.
  void* args[] = { (void*)&X, (void*)&emb, (void*)&Wout, (void*)&bout, (void*)&out,
                   (void*)&W0Th, (void*)&W0Tl, (void*)&WsTh, (void*)&WsTl,
                   (void*)&ST, (void*)&SH, (void*)&SL, (void*)&XNH, (void*)&XNL,
                   (void*)&bar, (void*)&wlo };
  hipError_t e = hipLaunchCooperativeKernel((void*)darts_coop, dim3(256), dim3(1024), args, 0, stream);
  if (e != hipSuccess){
    hipLaunchKernelGGL(darts_coop, dim3(256), dim3(1024), 0, stream,
                       X, emb, Wout, bout, out, W0Th, W0Tl, WsTh, WsTl,
                       ST, SH, SL, XNH, XNL, bar, wlo);
  }
}

// Round 5
// 52653.699 us; speedup vs baseline: 1.4978x; 1.2324x over previous
//
#include <hip/hip_runtime.h>

#define TT 512

typedef _Float16 f16;
typedef _Float16 half8 __attribute__((ext_vector_type(8)));
typedef float f32x4 __attribute__((ext_vector_type(4)));

#define MFMA(a,b,c) __builtin_amdgcn_mfma_f32_16x16x32_f16((a),(b),(c),0,0,0)
#define LOSC  2048.0f
#define RLOSC 0.00048828125f   // 1/2048

// LDS partial layout: per-wave region of 16 rows, row stride 18 floats.
#define RS  18
#define WSZ (16*RS)      // 288 floats per wave region
#define LSZ (16*WSZ)     // 4608 floats per buffer (18.4 KB)

__device__ __forceinline__ half8 ldh8(const f16* p){ return *(const half8*)p; }
__device__ __forceinline__ float sgm(float x){ return 1.f/(1.f+__expf(-x)); }
// act kinds: 0 tanh, 1 sigmoid, 2 relu, 3 identity
__device__ __forceinline__ float applyact(int k, float x){
  if (k==0) return tanhf(x);
  if (k==1) return sgm(x);
  if (k==2) return fmaxf(x,0.f);
  return x;
}

// ---- agent-coherent (sc1) memory ops: bypass stale L1/L2, talk to the
// coherence point directly. This is the same per-instruction mechanism the
// compiler uses for agent-scope atomics (proven working by the R4 barrier).
// State arrays use these; weights stay on the normal cached path and are
// never invalidated (no acquire fence anywhere in the loop).
__device__ __forceinline__ void issue_ld4_sc1(half8& d, const f16* p){
  asm volatile("global_load_dwordx4 %0, %1, off sc1" : "=&v"(d) : "v"(p) : "memory");
}
__device__ __forceinline__ void issue_ldf_sc1(float& d, const float* p){
  asm volatile("global_load_dword %0, %1, off sc1" : "=&v"(d) : "v"(p) : "memory");
}
__device__ __forceinline__ void vmwait(){
  asm volatile("s_waitcnt vmcnt(0)" ::: "memory");
  __builtin_amdgcn_sched_barrier(0);   // rule #18: block MFMA hoist past waitcnt
}
__device__ __forceinline__ void st_f32_sc1(float* p, float v){
  asm volatile("global_store_dword %0, %1, off sc1" :: "v"(p), "v"(v) : "memory");
}
__device__ __forceinline__ void st_f16_sc1(f16* p, f16 v){
  unsigned uv = (unsigned)__builtin_bit_cast(unsigned short, v);
  asm volatile("global_store_short %0, %1, off sc1" :: "v"(p), "v"(uv) : "memory");
}

// ---- grid barrier v4: release fence on arrive (orders sc1 stores before flag;
// L2 is ~clean so wbl2 has nothing to write back). NO acquire fence on wait —
// consumers read state via sc1, so no L2 invalidate is ever needed.
__device__ __forceinline__ void gbar_arrive(unsigned* bar, unsigned ph, int b, int tid){
  __syncthreads();
  if (tid==0){
    __builtin_amdgcn_fence(__ATOMIC_RELEASE, "agent");
    __hip_atomic_store(&bar[b*16], ph+1u, __ATOMIC_RELAXED, __HIP_MEMORY_SCOPE_AGENT);
  }
}

__device__ __forceinline__ void gbar_wait(unsigned* bar, unsigned ph, int b, int tid){
  const unsigned tgt = ph + 1u;
  if (b==0){
    if (tid<256){
      while (__hip_atomic_load(&bar[tid*16], __ATOMIC_RELAXED, __HIP_MEMORY_SCOPE_AGENT) < tgt)
        __builtin_amdgcn_s_sleep(2);
    }
    __syncthreads();
    if (tid==0)
      __hip_atomic_store(&bar[4096], tgt, __ATOMIC_RELAXED, __HIP_MEMORY_SCOPE_AGENT);
  }
  if (tid==0){
    while (__hip_atomic_load(&bar[4096], __ATOMIC_RELAXED, __HIP_MEMORY_SCOPE_AGENT) < tgt)
      __builtin_amdgcn_s_sleep(2);
  }
  __syncthreads();
}

// ---- MFMA core: A-tile via batched sc1 loads (fresh cross-XCD state),
// weights via normal cached loads (L2/L1-resident, never invalidated). -------
template<int NCH>
__device__ __forceinline__ void mm_core(
  const f16* __restrict__ Ap, const f16* __restrict__ Alp,
  const f16* __restrict__ Bg, const f16* __restrict__ Ba,
  const f16* __restrict__ Bgl, const f16* __restrict__ Bal,
  int wlo, float* __restrict__ Lg, float* __restrict__ La,
  int region, int q8, int l15)
{
  half8 AH[NCH], AL[NCH];
  #pragma unroll
  for (int c=0;c<NCH;c++){
    issue_ld4_sc1(AH[c], Ap+c*32);
    issue_ld4_sc1(AL[c], Alp+c*32);
  }
  vmwait();
  f32x4 g0={0,0,0,0},g1={0,0,0,0},a0={0,0,0,0},a1={0,0,0,0};
  #pragma unroll
  for (int c=0;c<NCH;c++){
    int s = c*32;
    half8 wg=ldh8(Bg+s), wa=ldh8(Ba+s);
    g0=MFMA(AH[c],wg,g0); a0=MFMA(AH[c],wa,a0);
    g1=MFMA(AL[c],wg,g1); a1=MFMA(AL[c],wa,a1);
    if (wlo){ g1=MFMA(AH[c],ldh8(Bgl+s),g1); a1=MFMA(AH[c],ldh8(Bal+s),a1); }
  }
  f32x4 gg = g0 + g1*RLOSC, aa = a0 + a1*RLOSC;
  const int base = region*WSZ + (q8>>1)*RS + l15;   // row-in-tile = q*4+rr
  #pragma unroll
  for (int rr=0;rr<4;rr++){
    Lg[base + rr*RS] = gg[rr];
    La[base + rr*RS] = aa[rr];
  }
}

// ---- standard node (K stride 1024 weights) ------------------------------------
template<int NCH>
__device__ __forceinline__ void node_std(
  const f16* __restrict__ SHs, const f16* __restrict__ SLs,
  const f16* __restrict__ Wh, const f16* __restrict__ Wl,
  float* __restrict__ Lg, float* __restrict__ La,
  int region, int kk, int m0, int c0, int q8, int l15, int wlo)
{
  const f16* Ap  = SHs + (m0+l15)*1024 + kk + q8;
  const f16* Alp = SLs + (m0+l15)*1024 + kk + q8;
  const f16* Bg  = Wh + (size_t)(c0+l15)*1024 + kk + q8;
  const f16* Ba  = Wh + (size_t)(1024+c0+l15)*1024 + kk + q8;
  const f16* Bgl = wlo ? Wl + (size_t)(c0+l15)*1024 + kk + q8 : Bg;
  const f16* Bal = wlo ? Wl + (size_t)(1024+c0+l15)*1024 + kk + q8 : Ba;
  mm_core<NCH>(Ap,Alp,Bg,Ba,Bgl,Bal,wlo,Lg,La,region,q8,l15);
}

// ---- reduce partials [r0, r0+nr), apply gate/act ------------------------------
// spv load issued sc1 up-front, overlapped with the LDS reduction.
__device__ __forceinline__ float fin_val(const float* __restrict__ Lg, const float* __restrict__ La,
  const float* __restrict__ ST, int t256, int m0, int c0, int r0, int nr, int sp, int actk)
{
  const int row = t256>>4, col = t256&15;
  float spv;
  issue_ldf_sc1(spv, ST + sp*65536 + (m0+row)*1024 + c0 + col);
  const int e = row*RS + col;
  float gs=0.f, as=0.f;
  for (int r=r0; r<r0+nr; ++r){ gs += Lg[r*WSZ+e]; as += La[r*WSZ+e]; }
  vmwait();
  return spv + sgm(gs)*(applyact(actk,as)-spv);
}

__device__ __forceinline__ void fin_write(const float* __restrict__ Lg, const float* __restrict__ La,
  float* __restrict__ ST, f16* __restrict__ SH, f16* __restrict__ SL,
  int t256, int m0, int c0, int r0, int nr, int sp, int so, int actk, bool hl)
{
  float s = fin_val(Lg, La, ST, t256, m0, c0, r0, nr, sp, actk);
  const int row = t256>>4, col = t256&15;
  const int idx = so*65536 + (m0+row)*1024 + c0 + col;
  st_f32_sc1(ST+idx, s);
  if (hl){ f16 hi=(f16)s; st_f16_sc1(SH+idx, hi); st_f16_sc1(SL+idx, (f16)((s-(float)hi)*LOSC)); }
}

// ------------------------------- persistent kernel ------------------------------
__global__ __launch_bounds__(1024,4) void darts_coop(
  const int* __restrict__ X, const float* __restrict__ emb,
  const float* __restrict__ Wout, const float* __restrict__ bout, float* __restrict__ out,
  const f16* __restrict__ W0Th, const f16* __restrict__ W0Tl,
  const f16* __restrict__ WsTh, const f16* __restrict__ WsTl,
  float* __restrict__ ST, f16* __restrict__ SH, f16* __restrict__ SL,
  f16* __restrict__ XNH, f16* __restrict__ XNL,
  unsigned* bar, int wlo)
{
  const int tid = threadIdx.x, b = blockIdx.x;
  const int wid = tid>>6, lane = tid&63, l15 = lane&15, q8 = (lane>>4)*8;
  // XCD swizzle: the 4 blocks sharing a weight stripe (same sct) land on one XCD.
  const int mt = (b>>3)&3, sct = (b&7)*8 + (b>>5);
  const int m0 = mt*16, c0 = sct*16;
  __shared__ float Lg[LSZ], La[LSZ];
  __shared__ float S6[256], S8[256];
  unsigned ph = 0;

  for (int t=0; t<TT; ++t){
    // ---- P0: node0 (A=[x|h], K=2048) + x(t+1) gather into alt buffer ----------
    if (t+1 < TT && tid < 256){
      int row = b>>2, col = ((b&3)<<8) + tid;
      int tok = X[(t+1)*64 + row];
      float v = emb[(size_t)tok*1024 + col];
      f16 hi=(f16)v;
      int xi = ((t+1)&1)*65536 + row*1024 + col;
      st_f16_sc1(XNH+xi, hi);
      st_f16_sc1(XNL+xi, (f16)((v-(float)hi)*LOSC));
    }
    {
      const f16* XH = XNH + (t&1)*65536;
      const f16* XL = XNL + (t&1)*65536;
      int kk = wid*128, ak = kk & 1023;
      const f16* Abh = (wid<8)? XH : SH;    // slot0 = h
      const f16* Abl = (wid<8)? XL : SL;
      const f16* Ap  = Abh + (m0+l15)*1024 + ak + q8;
      const f16* Alp = Abl + (m0+l15)*1024 + ak + q8;
      const f16* Bg  = W0Th + (size_t)(c0+l15)*2048 + kk + q8;
      const f16* Ba  = W0Th + (size_t)(1024+c0+l15)*2048 + kk + q8;
      const f16* Bgl = wlo ? W0Tl + (size_t)(c0+l15)*2048 + kk + q8 : Bg;
      const f16* Bal = wlo ? W0Tl + (size_t)(1024+c0+l15)*2048 + kk + q8 : Ba;
      mm_core<4>(Ap,Alp,Bg,Ba,Bgl,Bal,wlo,Lg,La,wid,q8,l15);
    }
    __syncthreads();
    if (tid<256) fin_write(Lg,La,ST,SH,SL, tid, m0,c0, 0,16, /*sp*/0, /*out*/1, /*tanh*/0, true);
    gbar_arrive(bar, ph, b, tid);
    gbar_wait(bar, ph, b, tid); ph++;

    // ---- P1: node1 (pred s0=slot1, Ws[0], sigmoid), 16 waves, K=1024 ----------
    node_std<2>(SH+1*65536, SL+1*65536, WsTh, WsTl, Lg, La, wid, wid*64, m0,c0,q8,l15,wlo);
    __syncthreads();
    if (tid<256) fin_write(Lg,La,ST,SH,SL, tid, m0,c0, 0,16, 1, 2, /*sigmoid*/1, true);
    gbar_arrive(bar, ph, b, tid);
    gbar_wait(bar, ph, b, tid); ph++;

    // ---- P2a: n2 (waves 0-7) || n3 (waves 8-15), both pred s1=slot2, relu -----
    if (wid<8)
      node_std<4>(SH+2*65536, SL+2*65536, WsTh+(size_t)1*2097152,
                  wlo? WsTl+(size_t)1*2097152 : (const f16*)0,
                  Lg, La, wid, (wid&7)*128, m0,c0,q8,l15,wlo);
    else
      node_std<4>(SH+2*65536, SL+2*65536, WsTh+(size_t)2*2097152,
                  wlo? WsTl+(size_t)2*2097152 : (const f16*)0,
                  Lg, La, wid, (wid&7)*128, m0,c0,q8,l15,wlo);
    __syncthreads();
    if (tid<256)      fin_write(Lg,La,ST,SH,SL, tid,     m0,c0, 0,8, 2, 3, /*relu*/2, true);
    else if (tid<512) fin_write(Lg,La,ST,SH,SL, tid-256, m0,c0, 8,8, 2, 4, /*relu*/2, true);
    __syncthreads();

    // ---- P2b: n4 (identity, pred s1), 16 waves, K=1024 ------------------------
    node_std<2>(SH+2*65536, SL+2*65536, WsTh+(size_t)3*2097152,
                wlo? WsTl+(size_t)3*2097152 : (const f16*)0,
                Lg, La, wid, wid*64, m0,c0,q8,l15,wlo);
    __syncthreads();
    if (tid<256) fin_write(Lg,La,ST,SH,SL, tid, m0,c0, 0,16, 2, 5, /*identity*/3, false);
    gbar_arrive(bar, ph, b, tid);
    gbar_wait(bar, ph, b, tid); ph++;

    // ---- P3: n5 (pred s2=slot3, tanh) || n7 (pred s3=slot4, tanh) -------------
    if (wid<8)
      node_std<4>(SH+3*65536, SL+3*65536, WsTh+(size_t)4*2097152,
                  wlo? WsTl+(size_t)4*2097152 : (const f16*)0,
                  Lg, La, wid, (wid&7)*128, m0,c0,q8,l15,wlo);
    else
      node_std<4>(SH+4*65536, SL+4*65536, WsTh+(size_t)6*2097152,
                  wlo? WsTl+(size_t)6*2097152 : (const f16*)0,
                  Lg, La, wid, (wid&7)*128, m0,c0,q8,l15,wlo);
    __syncthreads();
    if (tid<256)      fin_write(Lg,La,ST,SH,SL, tid,     m0,c0, 0,8, 3, 6, /*tanh*/0, true);
    else if (tid<512) fin_write(Lg,La,ST,SH,SL, tid-256, m0,c0, 8,8, 4, 8, /*tanh*/0, false);
    gbar_arrive(bar, ph, b, tid);
    gbar_wait(bar, ph, b, tid); ph++;

    // ---- P4: n6 (sigmoid) || n8 (relu), both pred s5=slot6; mean -> h ---------
    if (wid<8)
      node_std<4>(SH+6*65536, SL+6*65536, WsTh+(size_t)5*2097152,
                  wlo? WsTl+(size_t)5*2097152 : (const f16*)0,
                  Lg, La, wid, (wid&7)*128, m0,c0,q8,l15,wlo);
    else
      node_std<4>(SH+6*65536, SL+6*65536, WsTh+(size_t)7*2097152,
                  wlo? WsTl+(size_t)7*2097152 : (const f16*)0,
                  Lg, La, wid, (wid&7)*128, m0,c0,q8,l15,wlo);
    __syncthreads();
    if (tid<256)      S6[tid]     = fin_val(Lg,La,ST, tid,     m0,c0, 0,8, 6, /*sigmoid*/1);
    else if (tid<512) S8[tid-256] = fin_val(Lg,La,ST, tid-256, m0,c0, 8,8, 6, /*relu*/2);
    __syncthreads();
    if (tid<256){
      const int row = tid>>4, col = tid&15;
      const int idx = (m0+row)*1024 + c0 + col;
      float v2,v3,v4,v5,v6,v8;
      issue_ldf_sc1(v2, ST+2*65536+idx);
      issue_ldf_sc1(v3, ST+3*65536+idx);
      issue_ldf_sc1(v4, ST+4*65536+idx);
      issue_ldf_sc1(v5, ST+5*65536+idx);
      issue_ldf_sc1(v6, ST+6*65536+idx);
      issue_ldf_sc1(v8, ST+8*65536+idx);
      float slocal = S6[tid] + S8[tid];
      vmwait();
      float m = (v2+v3+v4+v5+v6+v8+slocal)*0.125f;
      st_f32_sc1(ST+idx, m);
      f16 hi=(f16)m;
      st_f16_sc1(SH+idx, hi);
      st_f16_sc1(SL+idx, (f16)((m-(float)hi)*LOSC));
    }
    gbar_arrive(bar, ph, b, tid);
    gbar_wait(bar, ph, b, tid); ph++;
  }

  // ---- final head: a_hat = h @ Wout + bout ; probs = softmax --------------------
  if (b==0){
    if (tid==0) __builtin_amdgcn_fence(__ATOMIC_ACQUIRE, "agent");
    __syncthreads();
    if (tid<256){
      int row = tid>>2, col = tid&3;
      float acc = bout[col];
      const float* hrow = ST + row*1024;
      #pragma unroll 8
      for (int k=0;k<1024;k++) acc += hrow[k]*Wout[k*4+col];
      out[row*4+col] = acc;
      float m = fmaxf(acc, __shfl_xor(acc,1));
      m = fmaxf(m, __shfl_xor(m,2));
      float e = __expf(acc-m);
      float ssum = e + __shfl_xor(e,1);
      ssum = ssum + __shfl_xor(ssum,2);
      out[256 + row*4+col] = e/ssum;
    }
  }
}

// ------------------------------- prep kernels -----------------------------------
__global__ void prep_x0(const int* __restrict__ X, const float* __restrict__ hidden,
  const float* __restrict__ emb, f16* __restrict__ XNH, f16* __restrict__ XNL,
  float* __restrict__ ST, f16* __restrict__ SH, f16* __restrict__ SL, unsigned* bar)
{
  int idx = blockIdx.x*256 + threadIdx.x;   // 65536 threads
  float hv = hidden[idx];
  ST[idx] = hv;
  f16 hh=(f16)hv; SH[idx]=hh; SL[idx]=(f16)((hv-(float)hh)*LOSC);
  int brow = idx>>10, k = idx&1023;
  int tok = X[brow];
  float v = emb[tok*1024+k];
  f16 xh=(f16)v; XNH[idx]=xh; XNL[idx]=(f16)((v-(float)xh)*LOSC);  // slot 0 (t=0)
  if (idx < 8192) bar[idx] = 0u;
}

__global__ void prep_w(const float* __restrict__ W0, const float* __restrict__ Ws,
  f16* __restrict__ W0Th, f16* __restrict__ W0Tl, f16* __restrict__ WsTh, f16* __restrict__ WsTl)
{
  __shared__ float L[64][65];
  int b = blockIdx.x, tid = threadIdx.x;
  const float* src; f16 *Dh, *Dl; int K, tk, tn;
  if (b < 1024){ src=W0; Dh=W0Th; Dl=W0Tl; K=2048; tk=b&31; tn=b>>5; }
  else { int bb=b-1024; int mi=bb>>9; int t2=bb&511; tk=t2&15; tn=t2>>4;
         src = Ws + (size_t)mi*1024*2048; Dh = WsTh + (size_t)mi*2097152;
         Dl = WsTl ? (WsTl + (size_t)mi*2097152) : (f16*)0; K=1024; }
  int k0 = tk*64, n0 = tn*64;
  int rr = tid>>6, cc = tid&63;
  #pragma unroll
  for (int j=0;j<16;j++){
    int r = j*4 + rr;
    L[cc][r] = src[(size_t)(k0+r)*2048 + n0+cc];
  }
  __syncthreads();
  #pragma unroll
  for (int j=0;j<16;j++){
    int n = j*4 + rr;
    float v = L[n][cc];
    f16 hi = (f16)v;
    Dh[(size_t)(n0+n)*K + k0+cc] = hi;
    if (Dl) Dl[(size_t)(n0+n)*K + k0+cc] = (f16)((v-(float)hi)*LOSC);
  }
}

__global__ void sentinel_k(float* __restrict__ out, float v){
  int i = blockIdx.x*256 + threadIdx.x;
  if (i < 512) out[i] = v;
}

// ------------------------------- launcher ----------------------------------------
extern "C" void kernel_launch(void* const* d_in, const int* in_sizes, int n_in,
                              void* d_out, int out_size, void* d_ws, size_t ws_size,
                              hipStream_t stream)
{
  const int*   X      = (const int*)  d_in[0];
  const float* hidden = (const float*)d_in[1];
  const float* emb    = (const float*)d_in[2];
  const float* W0     = (const float*)d_in[3];
  const float* Ws     = (const float*)d_in[4];
  const float* Wout   = (const float*)d_in[5];
  const float* bout   = (const float*)d_in[6];
  float* out = (float*)d_out;

  const size_t SZ_W0   = (size_t)2048*2048*2;      // 8.39 MB (f16)
  const size_t SZ_WS   = (size_t)8*2048*1024*2;    // 33.55 MB
  const size_t SZ_ST   = (size_t)10*65536*4;
  const size_t SZ_SHL  = (size_t)10*65536*2;
  const size_t SZ_XN   = (size_t)2*65536*2;        // double-buffered
  const size_t SZ_BAR  = 32768;

  auto pad = [](size_t x){ return (x + 255) & ~(size_t)255; };
  size_t need_red  = pad(SZ_W0) + pad(SZ_WS) + pad(SZ_ST) + 2*pad(SZ_SHL)
                   + 2*pad(SZ_XN) + pad(SZ_BAR);
  size_t need_full = need_red + pad(SZ_W0) + pad(SZ_WS);

  int wlo;
  if (ws_size >= need_full)      wlo = 1;
  else if (ws_size >= need_red)  wlo = 0;
  else { hipLaunchKernelGGL(sentinel_k, dim3(2), dim3(256), 0, stream, out, 1.0e6f); return; }

  char* w = (char*)d_ws; size_t off = 0;
  auto alloc = [&](size_t bytes)->void*{ void* p = w+off; off += (bytes+255)&~(size_t)255; return p; };
  f16* W0Th = (f16*)alloc(SZ_W0);
  f16* WsTh = (f16*)alloc(SZ_WS);
  f16* W0Tl = wlo ? (f16*)alloc(SZ_W0) : (f16*)0;
  f16* WsTl = wlo ? (f16*)alloc(SZ_WS) : (f16*)0;
  float* ST = (float*)alloc(SZ_ST);
  f16* SH   = (f16*)alloc(SZ_SHL);
  f16* SL   = (f16*)alloc(SZ_SHL);
  f16* XNH  = (f16*)alloc(SZ_XN);
  f16* XNL  = (f16*)alloc(SZ_XN);
  unsigned* bar = (unsigned*)alloc(SZ_BAR);

  hipLaunchKernelGGL(prep_x0, dim3(256), dim3(256), 0, stream,
                     X, hidden, emb, XNH, XNL, ST, SH, SL, bar);
  hipLaunchKernelGGL(prep_w, dim3(5120), dim3(256), 0, stream,
                     W0, Ws, W0Th, W0Tl, WsTh, WsTl);

  // 256 blocks x 1024 threads: 1 block/CU -> co-residency guaranteed.
  void* args[] = { (void*)&X, (void*)&emb, (void*)&Wout, (void*)&bout, (void*)&out,
                   (void*)&W0Th, (void*)&W0Tl, (void*)&WsTh, (void*)&WsTl,
                   (void*)&ST, (void*)&SH, (void*)&SL, (void*)&XNH, (void*)&XNL,
                   (void*)&bar, (void*)&wlo };
  hipError_t e = hipLaunchCooperativeKernel((void*)darts_coop, dim3(256), dim3(1024), args, 0, stream);
  if (e != hipSuccess){
    hipLaunchKernelGGL(darts_coop, dim3(256), dim3(1024), 0, stream,
                       X, emb, Wout, bout, out, W0Th, W0Tl, WsTh, WsTl,
                       ST, SH, SL, XNH, XNL, bar, wlo);
  }
}